// Round 1
// baseline (311.218 us; speedup 1.0000x reference)
//
#include <hip/hip_runtime.h>

// LatentTexture: quantize-STE (8b hi / 4b lo) + align_corners=True bilinear
// grid sample at 131072 uv points -> [131072, 16] fp32 (12 hi ch + 4 lo ch).
//
// Layout: one thread per (sample, channel). 16 threads share one uv point
// (broadcast load), each does 4 scattered texel loads + fused quantize +
// bilinear blend, then a perfectly coalesced store of out[s*16 + c].

#define NSAMP   131072
#define NCH     16          // 12 hi + 4 lo
#define HI_W    2048
#define LO_W    512

__global__ __launch_bounds__(256)
void latent_texture_kernel(const float2* __restrict__ uv,
                           const float*  __restrict__ hi,
                           const float*  __restrict__ lo,
                           float*        __restrict__ out)
{
    const int tid = blockIdx.x * 256 + threadIdx.x;
    const int s   = tid >> 4;      // sample index
    const int c   = tid & 15;      // output channel

    const float2 p = uv[s];        // 16-way broadcast within the group

    const float* tex;
    int W;
    float qmax, rq;
    if (c < 12) {
        tex  = hi + (size_t)c * (HI_W * HI_W);
        W    = HI_W;
        qmax = 255.0f;  rq = 1.0f / 255.0f;
    } else {
        tex  = lo + (size_t)(c - 12) * (LO_W * LO_W);
        W    = LO_W;
        qmax = 15.0f;   rq = 1.0f / 15.0f;
    }
    const int H = W;

    // Reference arithmetic: gx = u*2-1; ix = (gx+1)*0.5*(W-1)
    const float gx = p.x * 2.0f - 1.0f;
    const float gy = p.y * 2.0f - 1.0f;
    const float ix = (gx + 1.0f) * 0.5f * (float)(W - 1);
    const float iy = (gy + 1.0f) * 0.5f * (float)(H - 1);

    const float ix0f = floorf(ix);
    const float iy0f = floorf(iy);
    const float wx = ix - ix0f;
    const float wy = iy - iy0f;

    int ix0 = (int)ix0f;  ix0 = min(max(ix0, 0), W - 1);
    int iy0 = (int)iy0f;  iy0 = min(max(iy0, 0), H - 1);
    const int ix1 = min(ix0 + 1, W - 1);
    const int iy1 = min(iy0 + 1, H - 1);

    const float* r0 = tex + (size_t)iy0 * W;
    const float* r1 = tex + (size_t)iy1 * W;
    float v00 = r0[ix0];
    float v01 = r0[ix1];
    float v10 = r1[ix0];
    float v11 = r1[ix1];

    // quantize_ste forward value: round(clip(x,0,1)*qmax)/qmax (round half-even)
    v00 = rintf(fminf(fmaxf(v00, 0.0f), 1.0f) * qmax) * rq;
    v01 = rintf(fminf(fmaxf(v01, 0.0f), 1.0f) * qmax) * rq;
    v10 = rintf(fminf(fmaxf(v10, 0.0f), 1.0f) * qmax) * rq;
    v11 = rintf(fminf(fmaxf(v11, 0.0f), 1.0f) * qmax) * rq;

    const float omwx = 1.0f - wx;
    const float omwy = 1.0f - wy;
    const float res = v00 * omwy * omwx + v01 * omwy * wx
                    + v10 * wy   * omwx + v11 * wy   * wx;

    out[(size_t)s * NCH + c] = res;   // coalesced: consecutive lanes, consecutive addrs
}

extern "C" void kernel_launch(void* const* d_in, const int* in_sizes, int n_in,
                              void* d_out, int out_size, void* d_ws, size_t ws_size,
                              hipStream_t stream) {
    const float2* uv = (const float2*)d_in[0];          // [131072, 2] f32
    const float*  hi = (const float*)d_in[1];           // [1,12,2048,2048] f32
    const float*  lo = (const float*)d_in[2];           // [1,4,512,512] f32
    float* out = (float*)d_out;                         // [131072, 16] f32

    const int total  = NSAMP * NCH;                     // 2,097,152 threads
    const int blocks = total / 256;                     // 8192 blocks
    latent_texture_kernel<<<blocks, 256, 0, stream>>>(uv, hi, lo, out);
}

// Round 2
// 308.569 us; speedup vs baseline: 1.0086x; 1.0086x over previous
//
#include <hip/hip_runtime.h>

// LatentTexture: quantize-STE (8b hi / 4b lo) + align_corners bilinear sample.
// Two-pass: (1) streaming quantize + channel-last repack into d_ws
//           (2) scattered sample pass reading 16-B/4-B interleaved texels.
// Rationale: channel-first f32 layout wastes ~4KB of cache-line traffic per
// random sample; channel-last u8 cuts it to ~200B. Round-1 direct kernel: 311us.

#define NSAMP   131072
#define HI_W    2048
#define LO_W    512
#define HI_PIX  (HI_W * HI_W)          // 4,194,304
#define LO_PIX  (LO_W * LO_W)          // 262,144
#define HI_BLOCKS (HI_PIX / 4 / 256)   // 4096 (4 px/thread)
#define LO_BLOCKS (LO_PIX / 4 / 256)   // 256
#define WS_NEED ((size_t)HI_PIX * 16 + (size_t)LO_PIX * 4)  // 68,157,440 B

__device__ __forceinline__ unsigned int quant_u(float v, float qmax) {
    return (unsigned int)rintf(fminf(fmaxf(v, 0.0f), 1.0f) * qmax);
}

// ---- Pass 1: quantize + transpose to channel-last u8 -----------------------
__global__ __launch_bounds__(256)
void quant_pack_kernel(const float4* __restrict__ hi,   // [12][HI_PIX/4]
                       const float4* __restrict__ lo,   // [4][LO_PIX/4]
                       uint4* __restrict__ hiT,         // [HI_PIX] {ch0-3,ch4-7,ch8-11,0}
                       uint4* __restrict__ loT)         // [LO_PIX/4] 4 px/elem
{
    const int b = blockIdx.x;
    if (b < HI_BLOCKS) {
        const int t = b * 256 + threadIdx.x;            // 4 consecutive px
        unsigned int acc[4][3];
        #pragma unroll
        for (int j = 0; j < 4; ++j) acc[j][0] = acc[j][1] = acc[j][2] = 0u;
        #pragma unroll
        for (int c = 0; c < 12; ++c) {
            const float4 v = hi[(size_t)c * (HI_PIX / 4) + t];  // coalesced
            const float f[4] = {v.x, v.y, v.z, v.w};
            const int w = c >> 2, sh = (c & 3) * 8;
            #pragma unroll
            for (int j = 0; j < 4; ++j)
                acc[j][w] |= quant_u(f[j], 255.0f) << sh;
        }
        #pragma unroll
        for (int j = 0; j < 4; ++j)
            hiT[(size_t)t * 4 + j] = make_uint4(acc[j][0], acc[j][1], acc[j][2], 0u);
    } else {
        const int t = (b - HI_BLOCKS) * 256 + threadIdx.x;
        unsigned int acc[4] = {0u, 0u, 0u, 0u};
        #pragma unroll
        for (int c = 0; c < 4; ++c) {
            const float4 v = lo[(size_t)c * (LO_PIX / 4) + t];
            const float f[4] = {v.x, v.y, v.z, v.w};
            const int sh = c * 8;
            #pragma unroll
            for (int j = 0; j < 4; ++j)
                acc[j] |= quant_u(f[j], 15.0f) << sh;
        }
        loT[t] = make_uint4(acc[0], acc[1], acc[2], acc[3]);
    }
}

// ---- Pass 2: bilinear sample from interleaved u8 ---------------------------
__global__ __launch_bounds__(256)
void sample_kernel(const float2* __restrict__ uv,
                   const uint4* __restrict__ hiT,
                   const unsigned int* __restrict__ loT,
                   float4* __restrict__ out)
{
    const int s = blockIdx.x * 256 + threadIdx.x;
    const float2 p = uv[s];

    float res[16];

    // ---------- hi (2048x2048, 12 ch, qmax 255) ----------
    {
        const float gx = p.x * 2.0f - 1.0f, gy = p.y * 2.0f - 1.0f;
        const float ix = (gx + 1.0f) * 0.5f * (float)(HI_W - 1);
        const float iy = (gy + 1.0f) * 0.5f * (float)(HI_W - 1);
        const float ix0f = floorf(ix), iy0f = floorf(iy);
        const float wx = ix - ix0f, wy = iy - iy0f;
        int ix0 = min(max((int)ix0f, 0), HI_W - 1);
        int iy0 = min(max((int)iy0f, 0), HI_W - 1);
        const int ix1 = min(ix0 + 1, HI_W - 1);
        const int iy1 = min(iy0 + 1, HI_W - 1);
        const uint4 a00 = hiT[(size_t)iy0 * HI_W + ix0];
        const uint4 a01 = hiT[(size_t)iy0 * HI_W + ix1];
        const uint4 a10 = hiT[(size_t)iy1 * HI_W + ix0];
        const uint4 a11 = hiT[(size_t)iy1 * HI_W + ix1];
        const float w00 = (1.0f - wy) * (1.0f - wx), w01 = (1.0f - wy) * wx;
        const float w10 = wy * (1.0f - wx),          w11 = wy * wx;
        const unsigned int* u00 = (const unsigned int*)&a00;
        const unsigned int* u01 = (const unsigned int*)&a01;
        const unsigned int* u10 = (const unsigned int*)&a10;
        const unsigned int* u11 = (const unsigned int*)&a11;
        #pragma unroll
        for (int c = 0; c < 12; ++c) {
            const int w = c >> 2, sh = (c & 3) * 8;
            const float q00 = (float)((u00[w] >> sh) & 0xff);
            const float q01 = (float)((u01[w] >> sh) & 0xff);
            const float q10 = (float)((u10[w] >> sh) & 0xff);
            const float q11 = (float)((u11[w] >> sh) & 0xff);
            res[c] = (q00 * w00 + q01 * w01 + q10 * w10 + q11 * w11) * (1.0f / 255.0f);
        }
    }

    // ---------- lo (512x512, 4 ch, qmax 15) ----------
    {
        const float gx = p.x * 2.0f - 1.0f, gy = p.y * 2.0f - 1.0f;
        const float ix = (gx + 1.0f) * 0.5f * (float)(LO_W - 1);
        const float iy = (gy + 1.0f) * 0.5f * (float)(LO_W - 1);
        const float ix0f = floorf(ix), iy0f = floorf(iy);
        const float wx = ix - ix0f, wy = iy - iy0f;
        int ix0 = min(max((int)ix0f, 0), LO_W - 1);
        int iy0 = min(max((int)iy0f, 0), LO_W - 1);
        const int ix1 = min(ix0 + 1, LO_W - 1);
        const int iy1 = min(iy0 + 1, LO_W - 1);
        const unsigned int l00 = loT[iy0 * LO_W + ix0];
        const unsigned int l01 = loT[iy0 * LO_W + ix1];
        const unsigned int l10 = loT[iy1 * LO_W + ix0];
        const unsigned int l11 = loT[iy1 * LO_W + ix1];
        const float w00 = (1.0f - wy) * (1.0f - wx), w01 = (1.0f - wy) * wx;
        const float w10 = wy * (1.0f - wx),          w11 = wy * wx;
        #pragma unroll
        for (int c = 0; c < 4; ++c) {
            const int sh = c * 8;
            const float q00 = (float)((l00 >> sh) & 0xff);
            const float q01 = (float)((l01 >> sh) & 0xff);
            const float q10 = (float)((l10 >> sh) & 0xff);
            const float q11 = (float)((l11 >> sh) & 0xff);
            res[12 + c] = (q00 * w00 + q01 * w01 + q10 * w10 + q11 * w11) * (1.0f / 15.0f);
        }
    }

    // coalesced-ish store: each lane writes its 64-B segment; wave covers 16 KB
    #pragma unroll
    for (int k = 0; k < 4; ++k)
        out[(size_t)s * 4 + k] = make_float4(res[4*k], res[4*k+1], res[4*k+2], res[4*k+3]);
}

// ---- Fallback (round-1 direct kernel) if ws is unexpectedly small ----------
__global__ __launch_bounds__(256)
void direct_kernel(const float2* __restrict__ uv,
                   const float*  __restrict__ hi,
                   const float*  __restrict__ lo,
                   float*        __restrict__ out)
{
    const int tid = blockIdx.x * 256 + threadIdx.x;
    const int s = tid >> 4, c = tid & 15;
    const float2 p = uv[s];
    const float* tex; int W; float qmax, rq;
    if (c < 12) { tex = hi + (size_t)c * HI_PIX; W = HI_W; qmax = 255.0f; rq = 1.0f/255.0f; }
    else        { tex = lo + (size_t)(c-12) * LO_PIX; W = LO_W; qmax = 15.0f; rq = 1.0f/15.0f; }
    const float gx = p.x * 2.0f - 1.0f, gy = p.y * 2.0f - 1.0f;
    const float ix = (gx + 1.0f) * 0.5f * (float)(W - 1);
    const float iy = (gy + 1.0f) * 0.5f * (float)(W - 1);
    const float ix0f = floorf(ix), iy0f = floorf(iy);
    const float wx = ix - ix0f, wy = iy - iy0f;
    int ix0 = min(max((int)ix0f, 0), W - 1);
    int iy0 = min(max((int)iy0f, 0), W - 1);
    const int ix1 = min(ix0 + 1, W - 1), iy1 = min(iy0 + 1, W - 1);
    const float* r0 = tex + (size_t)iy0 * W;
    const float* r1 = tex + (size_t)iy1 * W;
    float v00 = rintf(fminf(fmaxf(r0[ix0],0.f),1.f)*qmax)*rq;
    float v01 = rintf(fminf(fmaxf(r0[ix1],0.f),1.f)*qmax)*rq;
    float v10 = rintf(fminf(fmaxf(r1[ix0],0.f),1.f)*qmax)*rq;
    float v11 = rintf(fminf(fmaxf(r1[ix1],0.f),1.f)*qmax)*rq;
    out[(size_t)s*16 + c] = v00*(1.f-wy)*(1.f-wx) + v01*(1.f-wy)*wx
                          + v10*wy*(1.f-wx)       + v11*wy*wx;
}

extern "C" void kernel_launch(void* const* d_in, const int* in_sizes, int n_in,
                              void* d_out, int out_size, void* d_ws, size_t ws_size,
                              hipStream_t stream) {
    const float2* uv = (const float2*)d_in[0];
    const float*  hi = (const float*)d_in[1];
    const float*  lo = (const float*)d_in[2];
    float* out = (float*)d_out;

    if (ws_size < WS_NEED) {   // ws_size is constant per session: graph-safe
        direct_kernel<<<(NSAMP * 16) / 256, 256, 0, stream>>>(uv, hi, lo, out);
        return;
    }

    uint4* hiT = (uint4*)d_ws;                                   // 64 MiB
    uint4* loT = (uint4*)((char*)d_ws + (size_t)HI_PIX * 16);    // 1 MiB

    quant_pack_kernel<<<HI_BLOCKS + LO_BLOCKS, 256, 0, stream>>>(
        (const float4*)hi, (const float4*)lo, hiT, loT);
    sample_kernel<<<NSAMP / 256, 256, 0, stream>>>(
        uv, hiT, (const unsigned int*)loT, (float4*)out);
}

// Round 4
// 292.372 us; speedup vs baseline: 1.0645x; 1.0554x over previous
//
#include <hip/hip_runtime.h>

// LatentTexture: quantize-STE (8b hi / 4b lo) + align_corners bilinear sample.
// Two-pass through d_ws:
//   pass 1: streaming quantize + channel-last u8 repack (1 px/thread,
//           NT loads on the touch-once f32 input, coalesced uint4 store)
//   pass 2: scattered bilinear sample; per sample 4x uint4 (hi) + 4x dword (lo)
//           taps ~= 2 cache lines/sample instead of ~32 in the f32 layout.
// R1 direct: 311us total. R2 (4px/thread repack): 308us. dur_us carries
// ~200us of in-stream harness restore/poison; kernel budget is the remainder.
// R3: __builtin_nontemporal_store needs native vector type, not HIP float4.

#define NSAMP   131072
#define HI_W    2048
#define LO_W    512
#define HI_PIX  (HI_W * HI_W)            // 4,194,304
#define LO_PIX  (LO_W * LO_W)            // 262,144
#define HI_PX_BLOCKS (HI_PIX / 256)      // 16384  (1 px/thread)
#define LO_PX_BLOCKS (LO_PIX / 256)      // 1024
#define WS_NEED ((size_t)HI_PIX * 16 + (size_t)LO_PIX * 4)

typedef float fx4 __attribute__((ext_vector_type(4)));   // NT-store-compatible

__device__ __forceinline__ unsigned int quant_u(float v, float qmax) {
    return (unsigned int)rintf(fminf(fmaxf(v, 0.0f), 1.0f) * qmax);
}

// ---- Pass 1: quantize + transpose to channel-last u8, 1 px/thread ----------
__global__ __launch_bounds__(256)
void quant_pack_kernel(const float* __restrict__ hi,     // [12][HI_PIX]
                       const float* __restrict__ lo,     // [4][LO_PIX]
                       uint4* __restrict__ hiT,          // [HI_PIX]
                       unsigned int* __restrict__ loT)   // [LO_PIX]
{
    const int b = blockIdx.x;
    if (b < HI_PX_BLOCKS) {
        const int p = b * 256 + threadIdx.x;
        unsigned int w0 = 0, w1 = 0, w2 = 0;
        #pragma unroll
        for (int c = 0; c < 4; ++c)
            w0 |= quant_u(__builtin_nontemporal_load(hi + (size_t)c * HI_PIX + p), 255.0f) << (c * 8);
        #pragma unroll
        for (int c = 4; c < 8; ++c)
            w1 |= quant_u(__builtin_nontemporal_load(hi + (size_t)c * HI_PIX + p), 255.0f) << ((c - 4) * 8);
        #pragma unroll
        for (int c = 8; c < 12; ++c)
            w2 |= quant_u(__builtin_nontemporal_load(hi + (size_t)c * HI_PIX + p), 255.0f) << ((c - 8) * 8);
        hiT[p] = make_uint4(w0, w1, w2, 0u);             // wave: 1KB contiguous
    } else {
        const int p = (b - HI_PX_BLOCKS) * 256 + threadIdx.x;
        unsigned int w = 0;
        #pragma unroll
        for (int c = 0; c < 4; ++c)
            w |= quant_u(__builtin_nontemporal_load(lo + (size_t)c * LO_PIX + p), 15.0f) << (c * 8);
        loT[p] = w;
    }
}

// ---- Pass 2: bilinear sample from interleaved u8 ---------------------------
__global__ __launch_bounds__(256)
void sample_kernel(const float2* __restrict__ uv,
                   const uint4* __restrict__ hiT,
                   const unsigned int* __restrict__ loT,
                   fx4* __restrict__ out)
{
    const int s = blockIdx.x * 256 + threadIdx.x;
    const float2 p = uv[s];

    float res[16];

    // ---------- hi (2048x2048, 12 ch, qmax 255) ----------
    {
        const float gx = p.x * 2.0f - 1.0f, gy = p.y * 2.0f - 1.0f;
        const float ix = (gx + 1.0f) * 0.5f * (float)(HI_W - 1);
        const float iy = (gy + 1.0f) * 0.5f * (float)(HI_W - 1);
        const float ix0f = floorf(ix), iy0f = floorf(iy);
        const float wx = ix - ix0f, wy = iy - iy0f;
        int ix0 = min(max((int)ix0f, 0), HI_W - 1);
        int iy0 = min(max((int)iy0f, 0), HI_W - 1);
        const int ix1 = min(ix0 + 1, HI_W - 1);
        const int iy1 = min(iy0 + 1, HI_W - 1);
        const uint4 a00 = hiT[(size_t)iy0 * HI_W + ix0];
        const uint4 a01 = hiT[(size_t)iy0 * HI_W + ix1];
        const uint4 a10 = hiT[(size_t)iy1 * HI_W + ix0];
        const uint4 a11 = hiT[(size_t)iy1 * HI_W + ix1];
        const float w00 = (1.0f - wy) * (1.0f - wx), w01 = (1.0f - wy) * wx;
        const float w10 = wy * (1.0f - wx),          w11 = wy * wx;
        const unsigned int* u00 = (const unsigned int*)&a00;
        const unsigned int* u01 = (const unsigned int*)&a01;
        const unsigned int* u10 = (const unsigned int*)&a10;
        const unsigned int* u11 = (const unsigned int*)&a11;
        #pragma unroll
        for (int c = 0; c < 12; ++c) {
            const int w = c >> 2, sh = (c & 3) * 8;
            const float q00 = (float)((u00[w] >> sh) & 0xff);
            const float q01 = (float)((u01[w] >> sh) & 0xff);
            const float q10 = (float)((u10[w] >> sh) & 0xff);
            const float q11 = (float)((u11[w] >> sh) & 0xff);
            res[c] = (q00 * w00 + q01 * w01 + q10 * w10 + q11 * w11) * (1.0f / 255.0f);
        }
    }

    // ---------- lo (512x512, 4 ch, qmax 15) ----------
    {
        const float gx = p.x * 2.0f - 1.0f, gy = p.y * 2.0f - 1.0f;
        const float ix = (gx + 1.0f) * 0.5f * (float)(LO_W - 1);
        const float iy = (gy + 1.0f) * 0.5f * (float)(LO_W - 1);
        const float ix0f = floorf(ix), iy0f = floorf(iy);
        const float wx = ix - ix0f, wy = iy - iy0f;
        int ix0 = min(max((int)ix0f, 0), LO_W - 1);
        int iy0 = min(max((int)iy0f, 0), LO_W - 1);
        const int ix1 = min(ix0 + 1, LO_W - 1);
        const int iy1 = min(iy0 + 1, LO_W - 1);
        const unsigned int l00 = loT[iy0 * LO_W + ix0];
        const unsigned int l01 = loT[iy0 * LO_W + ix1];
        const unsigned int l10 = loT[iy1 * LO_W + ix0];
        const unsigned int l11 = loT[iy1 * LO_W + ix1];
        const float w00 = (1.0f - wy) * (1.0f - wx), w01 = (1.0f - wy) * wx;
        const float w10 = wy * (1.0f - wx),          w11 = wy * wx;
        #pragma unroll
        for (int c = 0; c < 4; ++c) {
            const int sh = c * 8;
            const float q00 = (float)((l00 >> sh) & 0xff);
            const float q01 = (float)((l01 >> sh) & 0xff);
            const float q10 = (float)((l10 >> sh) & 0xff);
            const float q11 = (float)((l11 >> sh) & 0xff);
            res[12 + c] = (q00 * w00 + q01 * w01 + q10 * w10 + q11 * w11) * (1.0f / 15.0f);
        }
    }

    #pragma unroll
    for (int k = 0; k < 4; ++k) {
        fx4 v = { res[4*k], res[4*k+1], res[4*k+2], res[4*k+3] };
        __builtin_nontemporal_store(v, &out[(size_t)s * 4 + k]);
    }
}

// ---- Fallback (round-1 direct kernel) if ws is unexpectedly small ----------
__global__ __launch_bounds__(256)
void direct_kernel(const float2* __restrict__ uv,
                   const float*  __restrict__ hi,
                   const float*  __restrict__ lo,
                   float*        __restrict__ out)
{
    const int tid = blockIdx.x * 256 + threadIdx.x;
    const int s = tid >> 4, c = tid & 15;
    const float2 p = uv[s];
    const float* tex; int W; float qmax, rq;
    if (c < 12) { tex = hi + (size_t)c * HI_PIX; W = HI_W; qmax = 255.0f; rq = 1.0f/255.0f; }
    else        { tex = lo + (size_t)(c-12) * LO_PIX; W = LO_W; qmax = 15.0f; rq = 1.0f/15.0f; }
    const float gx = p.x * 2.0f - 1.0f, gy = p.y * 2.0f - 1.0f;
    const float ix = (gx + 1.0f) * 0.5f * (float)(W - 1);
    const float iy = (gy + 1.0f) * 0.5f * (float)(W - 1);
    const float ix0f = floorf(ix), iy0f = floorf(iy);
    const float wx = ix - ix0f, wy = iy - iy0f;
    int ix0 = min(max((int)ix0f, 0), W - 1);
    int iy0 = min(max((int)iy0f, 0), W - 1);
    const int ix1 = min(ix0 + 1, W - 1), iy1 = min(iy0 + 1, W - 1);
    const float* r0 = tex + (size_t)iy0 * W;
    const float* r1 = tex + (size_t)iy1 * W;
    float v00 = rintf(fminf(fmaxf(r0[ix0],0.f),1.f)*qmax)*rq;
    float v01 = rintf(fminf(fmaxf(r0[ix1],0.f),1.f)*qmax)*rq;
    float v10 = rintf(fminf(fmaxf(r1[ix0],0.f),1.f)*qmax)*rq;
    float v11 = rintf(fminf(fmaxf(r1[ix1],0.f),1.f)*qmax)*rq;
    out[(size_t)s*16 + c] = v00*(1.f-wy)*(1.f-wx) + v01*(1.f-wy)*wx
                          + v10*wy*(1.f-wx)       + v11*wy*wx;
}

extern "C" void kernel_launch(void* const* d_in, const int* in_sizes, int n_in,
                              void* d_out, int out_size, void* d_ws, size_t ws_size,
                              hipStream_t stream) {
    const float2* uv = (const float2*)d_in[0];
    const float*  hi = (const float*)d_in[1];
    const float*  lo = (const float*)d_in[2];
    float* out = (float*)d_out;

    if (ws_size < WS_NEED) {
        direct_kernel<<<(NSAMP * 16) / 256, 256, 0, stream>>>(uv, hi, lo, out);
        return;
    }

    uint4* hiT = (uint4*)d_ws;                                   // 64 MiB
    unsigned int* loT = (unsigned int*)((char*)d_ws + (size_t)HI_PIX * 16);  // 1 MiB

    quant_pack_kernel<<<HI_PX_BLOCKS + LO_PX_BLOCKS, 256, 0, stream>>>(hi, lo, hiT, loT);
    sample_kernel<<<NSAMP / 256, 256, 0, stream>>>(uv, hiT, loT, (fx4*)out);
}